// Round 1
// baseline (318.571 us; speedup 1.0000x reference)
//
#include <hip/hip_runtime.h>

// Problem constants (from reference): B=32, L=7, M=6, C=3, H=128, W=128, TOP_K=3
#define B_    32
#define L_    7
#define M_    6
#define C_    3
#define H_    128
#define W_    128
#define TOPK  3

// out[b,l,k,:,:] = imgs[b, l, topk_idx(b,l,k), 0, :, :]
// (the -w+w straight-through term is numerically ~exact identity in fp32;
//  error <= ~2 ulp * |img|, vastly below the 0.101 absmax threshold)
__global__ __launch_bounds__(256) void MT2VEncoderFusion_gather(
    const float* __restrict__ imgs,   // (B,L,M,C,H,W)
    const float* __restrict__ wts,    // (B,L,M)
    float* __restrict__ out)          // (B,L,TOPK,H,W)
{
    const int plane = blockIdx.x;        // (b*L + l)*TOPK + k, 0..671
    const int bl    = plane / TOPK;      // b*L + l
    const int k     = plane - bl * TOPK;

    // --- top-k over the 6 weights for this (b,l); every thread redundantly ---
    const float* wp = wts + bl * M_;
    float v[M_];
    #pragma unroll
    for (int m = 0; m < M_; ++m) v[m] = wp[m];

    int sel = 0;
    bool excluded[M_];
    #pragma unroll
    for (int m = 0; m < M_; ++m) excluded[m] = false;

    // select (k+1) times; strict '>' keeps lowest index on ties, matching lax.top_k
    for (int t = 0; t <= k; ++t) {
        float best = -__builtin_inff();
        sel = 0;
        #pragma unroll
        for (int m = 0; m < M_; ++m) {
            if (!excluded[m] && v[m] > best) { best = v[m]; sel = m; }
        }
        excluded[sel] = true;
    }

    // --- copy one contiguous 128x128 plane (channel 0) with float4 loads ---
    const size_t HW = (size_t)H_ * W_;                       // 16384 floats
    const float4* __restrict__ src =
        (const float4*)(imgs + ((size_t)bl * M_ + sel) * C_ * HW);
    float4* __restrict__ dst = (float4*)(out + (size_t)plane * HW);

    const int n4      = (int)(HW / 4);          // 4096 float4 per plane
    const int slice   = n4 / gridDim.y;         // per-block share
    const int base    = blockIdx.y * slice;

    for (int i = threadIdx.x; i < slice; i += blockDim.x) {
        dst[base + i] = src[base + i];
    }
}

extern "C" void kernel_launch(void* const* d_in, const int* in_sizes, int n_in,
                              void* d_out, int out_size, void* d_ws, size_t ws_size,
                              hipStream_t stream) {
    const float* imgs = (const float*)d_in[0];  // (32,7,6,3,128,128) fp32
    const float* wts  = (const float*)d_in[1];  // (32,7,6) fp32
    float* out        = (float*)d_out;          // (32,7,3,128,128) fp32

    // 672 planes x 4 slices = 2688 blocks (~10/CU), 256 threads, 16 KB copy each
    dim3 grid(B_ * L_ * TOPK, 4);
    MT2VEncoderFusion_gather<<<grid, 256, 0, stream>>>(imgs, wts, out);
}

// Round 3
// 314.510 us; speedup vs baseline: 1.0129x; 1.0129x over previous
//
#include <hip/hip_runtime.h>

// Problem constants (from reference): B=32, L=7, M=6, C=3, H=128, W=128, TOP_K=3
#define B_    32
#define L_    7
#define M_    6
#define C_    3
#define H_    128
#define W_    128
#define TOPK  3

// Native clang vector type — HIP's float4 is a struct and is rejected by
// __builtin_nontemporal_{load,store}; ext_vector_type(4) float is accepted.
typedef float vfloat4 __attribute__((ext_vector_type(4)));

// out[b,l,k,:,:] = imgs[b, l, topk_idx(b,l,k), 0, :, :]
// The reference's masks = hard - stop_grad(w) + w is numerically the one-hot
// `hard` in forward (verified: absmax 0.0 in round 1), so the einsum is a
// pure plane gather: minimum traffic 44 MB read + 44 MB write = 88 MB.
__global__ __launch_bounds__(256) void MT2VEncoderFusion_gather(
    const float* __restrict__ imgs,   // (B,L,M,C,H,W)
    const float* __restrict__ wts,    // (B,L,M)
    float* __restrict__ out)          // (B,L,TOPK,H,W)
{
    const int plane = blockIdx.x;        // (b*L + l)*TOPK + k, 0..671
    const int bl    = plane / TOPK;      // b*L + l
    const int k     = plane - bl * TOPK;

    // --- top-k over the 6 weights for this (b,l); wave-uniform (s_load'able) ---
    const float* wp = wts + bl * M_;
    float v[M_];
    #pragma unroll
    for (int m = 0; m < M_; ++m) v[m] = wp[m];

    int sel = 0;
    bool excluded[M_];
    #pragma unroll
    for (int m = 0; m < M_; ++m) excluded[m] = false;

    // select (k+1) times; strict '>' keeps lowest index on ties, matching lax.top_k
    for (int t = 0; t <= k; ++t) {
        float best = -__builtin_inff();
        sel = 0;
        #pragma unroll
        for (int m = 0; m < M_; ++m) {
            if (!excluded[m] && v[m] > best) { best = v[m]; sel = m; }
        }
        excluded[sel] = true;
    }

    // --- copy one contiguous 128x128 fp32 plane (channel 0), nontemporal ---
    const size_t HW = (size_t)H_ * W_;                       // 16384 floats
    const vfloat4* __restrict__ src =
        (const vfloat4*)(imgs + ((size_t)bl * M_ + sel) * C_ * HW);
    vfloat4* __restrict__ dst = (vfloat4*)(out + (size_t)plane * HW);

    const int n4    = (int)(HW / 4);            // 4096 vfloat4 per plane
    const int slice = n4 / gridDim.y;           // 1024 vfloat4 per block
    const int base  = blockIdx.y * slice;

    #pragma unroll
    for (int j = 0; j < 4; ++j) {               // slice/256 == 4 iterations
        const int i = base + j * 256 + threadIdx.x;
        vfloat4 t = __builtin_nontemporal_load(&src[i]);
        __builtin_nontemporal_store(t, &dst[i]);
    }
}

extern "C" void kernel_launch(void* const* d_in, const int* in_sizes, int n_in,
                              void* d_out, int out_size, void* d_ws, size_t ws_size,
                              hipStream_t stream) {
    const float* imgs = (const float*)d_in[0];  // (32,7,6,3,128,128) fp32
    const float* wts  = (const float*)d_in[1];  // (32,7,6) fp32
    float* out        = (float*)d_out;          // (32,7,3,128,128) fp32

    // 672 planes x 4 slices = 2688 blocks (~10/CU), 256 threads, 16 KB copy each
    dim3 grid(B_ * L_ * TOPK, 4);
    MT2VEncoderFusion_gather<<<grid, 256, 0, stream>>>(imgs, wts, out);
}